// Round 8
// baseline (125.594 us; speedup 1.0000x reference)
//
#include <hip/hip_runtime.h>
#include <hip/hip_bf16.h>

// flex_conv via MFMA + register-marching waves (no LDS, no barriers).
// t[k=ic*4+d][pixel]: t_d = ctr_d*Xs - PX_d (d<3), t_3 = Xs
// out[o][pixel] = Kmat[o][k] . t[k][pixel]  -> 16x16x32 bf16 MFMA
// (A[m=p][k=c*8+..], B[k][n=p], D row=c*4+r col=p — validated R2-R7).
//
// Wave = 16-col strip, marches MR=8 output rows. 3-row ring of pre-reduced
// row partials (per t: rsx, r0,r1,r2; plus pts centers) lives in registers.
// Step s: issue 7 float4 loads for input row i0+s+3 (next window row),
// compute+MFMA+store output row i0+s from the ring, fold arrived row in.
// Loads overlap the full compute phase -> latency exposed only at priming.

#define HH 64
#define WW 512
#define HP 62
#define WP 510
#define IC 16
#define OC 32
#define BS 16
#define MR 8            // output rows marched per wave
#define YS 8            // row segments (last clamps to i0=54)

typedef __attribute__((ext_vector_type(8))) short short8;
typedef __attribute__((ext_vector_type(4))) float f32x4;
struct __attribute__((packed, aligned(4))) F4U { float x, y, z, w; };

static __device__ __forceinline__ short f2bf(float f) {
    union { __hip_bfloat16 h; short s; } u;
    u.h = __float2bfloat16(f);
    return u.s;
}

struct RowRed {
    float rsx[4], r0[4], r1[4], r2[4];   // per ic-group window-row partials
    float pm0, pm1, pm2;                 // pts center taps of this row
};

template<bool EDGE>
static __device__ __forceinline__ RowRed reduceRow(const F4U xv[4], const F4U pv[3], bool sh)
{
    RowRed rr;
    const float a0 = (EDGE && sh) ? pv[0].y : pv[0].x;
    const float m0 = (EDGE && sh) ? pv[0].z : pv[0].y;
    const float z0 = (EDGE && sh) ? pv[0].w : pv[0].z;
    const float a1 = (EDGE && sh) ? pv[1].y : pv[1].x;
    const float m1 = (EDGE && sh) ? pv[1].z : pv[1].y;
    const float z1 = (EDGE && sh) ? pv[1].w : pv[1].z;
    const float a2 = (EDGE && sh) ? pv[2].y : pv[2].x;
    const float m2 = (EDGE && sh) ? pv[2].z : pv[2].y;
    const float z2 = (EDGE && sh) ? pv[2].w : pv[2].z;
    rr.pm0 = m0; rr.pm1 = m1; rr.pm2 = m2;
    #pragma unroll
    for (int t = 0; t < 4; ++t) {
        const float xa = (EDGE && sh) ? xv[t].y : xv[t].x;
        const float xm = (EDGE && sh) ? xv[t].z : xv[t].y;
        const float xz = (EDGE && sh) ? xv[t].w : xv[t].z;
        rr.rsx[t] = xa + xm + xz;
        float v0 = a0 * xa; v0 = fmaf(m0, xm, v0); v0 = fmaf(z0, xz, v0);
        float v1 = a1 * xa; v1 = fmaf(m1, xm, v1); v1 = fmaf(z1, xz, v1);
        float v2 = a2 * xa; v2 = fmaf(m2, xm, v2); v2 = fmaf(z2, xz, v2);
        rr.r0[t] = v0; rr.r1[t] = v1; rr.r2[t] = v2;
    }
    return rr;
}

template<bool EDGE>
static __device__ __forceinline__ void march(
    const float* __restrict__ x, const float* __restrict__ kern,
    const float* __restrict__ pts, float* __restrict__ out,
    int b, int i0, int j0, int lane)
{
    const int p = lane & 15;
    const int c = lane >> 4;
    const int j = j0 + p;
    const int jl = (EDGE && j > WW - 4) ? (WW - 4) : j;
    const bool sh = EDGE && (j > WW - 4);

    const float* xb = x + (size_t)b * IC * HH * WW;
    const float* pb = pts + (size_t)b * 3 * HH * WW;

    // 32-bit plane offsets (uniform SGPR base + per-lane voffset addressing)
    unsigned xoff[4], poff[3];
    #pragma unroll
    for (int t = 0; t < 4; ++t) {
        const int ic = (t >> 1) * 8 + 2 * c + (t & 1);
        xoff[t] = (unsigned)(ic * HH * WW + jl);
    }
    #pragma unroll
    for (int d = 0; d < 3; ++d) poff[d] = (unsigned)(d * HH * WW + jl);

    // ---- A fragments: Kmat rows o=p / o=16+p, k-chunks c*8 / 32+c*8 ----
    short8 a0lo, a0hi, a1lo, a1hi;
    {
        const float4* k0v = (const float4*)(kern + (size_t)p * 64 + c * 8);
        const float4* k1v = (const float4*)(kern + (size_t)(16 + p) * 64 + c * 8);
        float4 v0a = k0v[0], v0b = k0v[1], v0c = k0v[8], v0d = k0v[9];
        float4 v1a = k1v[0], v1b = k1v[1], v1c = k1v[8], v1d = k1v[9];
        a0lo[0]=f2bf(v0a.x); a0lo[1]=f2bf(v0a.y); a0lo[2]=f2bf(v0a.z); a0lo[3]=f2bf(v0a.w);
        a0lo[4]=f2bf(v0b.x); a0lo[5]=f2bf(v0b.y); a0lo[6]=f2bf(v0b.z); a0lo[7]=f2bf(v0b.w);
        a0hi[0]=f2bf(v0c.x); a0hi[1]=f2bf(v0c.y); a0hi[2]=f2bf(v0c.z); a0hi[3]=f2bf(v0c.w);
        a0hi[4]=f2bf(v0d.x); a0hi[5]=f2bf(v0d.y); a0hi[6]=f2bf(v0d.z); a0hi[7]=f2bf(v0d.w);
        a1lo[0]=f2bf(v1a.x); a1lo[1]=f2bf(v1a.y); a1lo[2]=f2bf(v1a.z); a1lo[3]=f2bf(v1a.w);
        a1lo[4]=f2bf(v1b.x); a1lo[5]=f2bf(v1b.y); a1lo[6]=f2bf(v1b.z); a1lo[7]=f2bf(v1b.w);
        a1hi[0]=f2bf(v1c.x); a1hi[1]=f2bf(v1c.y); a1hi[2]=f2bf(v1c.z); a1hi[3]=f2bf(v1c.w);
        a1hi[4]=f2bf(v1d.x); a1hi[5]=f2bf(v1d.y); a1hi[6]=f2bf(v1d.z); a1hi[7]=f2bf(v1d.w);
    }

    // ---- prime the ring with input rows i0, i0+1, i0+2 ----
    F4U x0v[4], p0v[3], x1v[4], p1v[3], x2v[4], p2v[3];
    {
        const unsigned r0o = (unsigned)(i0 * WW);
        const unsigned r1o = r0o + WW;
        const unsigned r2o = r1o + WW;
        #pragma unroll
        for (int t = 0; t < 4; ++t) {
            x0v[t] = *(const F4U*)(xb + xoff[t] + r0o);
            x1v[t] = *(const F4U*)(xb + xoff[t] + r1o);
            x2v[t] = *(const F4U*)(xb + xoff[t] + r2o);
        }
        #pragma unroll
        for (int d = 0; d < 3; ++d) {
            p0v[d] = *(const F4U*)(pb + poff[d] + r0o);
            p1v[d] = *(const F4U*)(pb + poff[d] + r1o);
            p2v[d] = *(const F4U*)(pb + poff[d] + r2o);
        }
    }
    RowRed ring0 = reduceRow<EDGE>(x0v, p0v, sh);
    RowRed ring1 = reduceRow<EDGE>(x1v, p1v, sh);
    RowRed ring2 = reduceRow<EDGE>(x2v, p2v, sh);

    float* ob0 = out + (size_t)b * OC * HP * WP + (size_t)i0 * WP + j;

    // ---- march ----
    #pragma unroll
    for (int s = 0; s < MR; ++s) {
        // prefetch input row i0+s+3 (needed by step s+1); overlaps this step's compute
        F4U nx[4], np[3];
        if (s < MR - 1) {
            const unsigned ro = (unsigned)((i0 + s + 3) * WW);
            #pragma unroll
            for (int t = 0; t < 4; ++t) nx[t] = *(const F4U*)(xb + xoff[t] + ro);
            #pragma unroll
            for (int d = 0; d < 3; ++d) np[d] = *(const F4U*)(pb + poff[d] + ro);
        }

        // combine ring -> per-pixel t values
        const float c0 = ring1.pm0, c1 = ring1.pm1, c2 = ring1.pm2;
        short8 blo, bhi;
        #pragma unroll
        for (int t = 0; t < 4; ++t) {
            const float xs = ring0.rsx[t] + ring1.rsx[t] + ring2.rsx[t];
            const float q0 = ring0.r0[t] + ring1.r0[t] + ring2.r0[t];
            const float q1 = ring0.r1[t] + ring1.r1[t] + ring2.r1[t];
            const float q2 = ring0.r2[t] + ring1.r2[t] + ring2.r2[t];
            const short e0 = f2bf(fmaf(c0, xs, -q0));
            const short e1 = f2bf(fmaf(c1, xs, -q1));
            const short e2 = f2bf(fmaf(c2, xs, -q2));
            const short e3 = f2bf(xs);
            const int sl = (t & 1) * 4;
            if (t < 2) { blo[sl+0]=e0; blo[sl+1]=e1; blo[sl+2]=e2; blo[sl+3]=e3; }
            else       { bhi[sl+0]=e0; bhi[sl+1]=e1; bhi[sl+2]=e2; bhi[sl+3]=e3; }
        }

        f32x4 acc0 = {0.f,0.f,0.f,0.f}, acc1 = {0.f,0.f,0.f,0.f};
        acc0 = __builtin_amdgcn_mfma_f32_16x16x32_bf16(a0lo, blo, acc0, 0, 0, 0);
        acc0 = __builtin_amdgcn_mfma_f32_16x16x32_bf16(a0hi, bhi, acc0, 0, 0, 0);
        acc1 = __builtin_amdgcn_mfma_f32_16x16x32_bf16(a1lo, blo, acc1, 0, 0, 0);
        acc1 = __builtin_amdgcn_mfma_f32_16x16x32_bf16(a1hi, bhi, acc1, 0, 0, 0);

        if (j < WP) {
            float* ob = ob0 + (size_t)s * WP;
            #pragma unroll
            for (int r = 0; r < 4; ++r) {
                const int o = c * 4 + r;
                ob[(size_t)o * HP * WP]        = acc0[r];
                ob[(size_t)(o + 16) * HP * WP] = acc1[r];
            }
        }

        // rotate ring; fold the prefetched row in
        ring0 = ring1;
        ring1 = ring2;
        if (s < MR - 1) ring2 = reduceRow<EDGE>(nx, np, sh);
    }
}

__global__ __launch_bounds__(256, 3) void flex_conv_march(
    const float* __restrict__ x, const float* __restrict__ kern,
    const float* __restrict__ pts, float* __restrict__ out)
{
    const int tid = threadIdx.x;
    const int lane = tid & 63;
    const int wave = tid >> 6;
    const int strip = blockIdx.x * 4 + wave;   // 0..31
    const int j0 = strip * 16;
    int i0 = blockIdx.y * MR;                  // 0,8,..,56
    if (i0 > HP - MR) i0 = HP - MR;            // 54 (rows 54-61; overlap rewrite identical)
    const int b = blockIdx.z;

    if (strip == 31) march<true >(x, kern, pts, out, b, i0, j0, lane);
    else             march<false>(x, kern, pts, out, b, i0, j0, lane);
}

extern "C" void kernel_launch(void* const* d_in, const int* in_sizes, int n_in,
                              void* d_out, int out_size, void* d_ws, size_t ws_size,
                              hipStream_t stream)
{
    const float* x    = (const float*)d_in[0];
    const float* kern = (const float*)d_in[1];
    const float* pts  = (const float*)d_in[2];
    float* out = (float*)d_out;

    dim3 block(256, 1, 1);
    dim3 grid(8, YS, BS);   // 8 col-groups x 8 row-segments x 16 batch = 1024 blocks, 4096 waves
    flex_conv_march<<<grid, block, 0, stream>>>(x, kern, pts, out);
}

// Round 9
// 116.001 us; speedup vs baseline: 1.0827x; 1.0827x over previous
//
#include <hip/hip_runtime.h>
#include <hip/hip_bf16.h>

// flex_conv via MFMA + async LDS staging, tuned for RESIDENCY.
// t[k=ic*4+d][pixel]: t_d = ctr_d*Xs - PX_d (d<3), t_3 = Xs
// out[o][pixel] = Kmat[o][k] . t[k][pixel]  -> 16x16x32 bf16 MFMA
// (A[m=p][k=c*8+..], B[k][n=p], D row=c*4+r col=p — validated R2-R8).
//
// Block = 512 thr (8 waves) owns 128 cols x RB=3 output rows.
// Stage TR=5 rows x 19 planes x 136 cols into LDS (51.7 KB) via
// global_load_lds -> 3 blocks/CU by LDS = 24 waves/CU resident (75%).
// LDS layout [rr][plane][136]: x c-group stride = 2 planes = 272 floats
// = 16 mod 32 banks -> 2-way conflicts only (free per m136).
// Single barrier per block; 3 independent blocks/CU overlap each other's
// stage drains.

#define HH 64
#define WW 512
#define HP 62
#define WP 510
#define IC 16
#define OC 32
#define BS 16
#define RB 3              // output rows per block
#define TR (RB + 2)       // staged input rows = 5
#define TC 128            // output cols per block
#define LCP 136           // padded staged cols (130 needed; 136 = 34 chunks)
#define CPRW 34           // 16-B chunks per (rr,plane) row
#define NPL 19            // planes: 16 x + 3 pts
#define NCH (TR * NPL * CPRW)   // 3230 chunks
#define NTHR 512
#define NRND 7            // ceil(3230/512)

typedef __attribute__((ext_vector_type(8))) short short8;
typedef __attribute__((ext_vector_type(4))) float f32x4;

static __device__ __forceinline__ short f2bf(float f) {
    union { __hip_bfloat16 h; short s; } u;
    u.h = __float2bfloat16(f);
    return u.s;
}

__global__ __launch_bounds__(NTHR, 4) void flex_conv_res(
    const float* __restrict__ x, const float* __restrict__ kern,
    const float* __restrict__ pts, float* __restrict__ out)
{
    __shared__ float lds[TR * NPL * LCP];   // 12920 floats = 51680 B

    const int tid = threadIdx.x;
    const int j0 = blockIdx.x * TC;
    int i0 = blockIdx.y * RB;               // 0,3,..,60
    if (i0 > HP - RB) i0 = HP - RB;         // 59 (dup rows rewritten identically)
    const int b = blockIdx.z;

    const float* xb = x + (size_t)b * IC * HH * WW;
    const float* pb = pts + (size_t)b * 3 * HH * WW;

    // ---- async staging: 3230 16-B chunks over 512 threads ----
    #pragma unroll
    for (int rnd = 0; rnd < NRND; ++rnd) {
        const int cid = rnd * NTHR + tid;
        if (cid < NCH) {
            const int row = cid / CPRW;          // 0..94 = rr*NPL + plane
            const int ch = cid - row * CPRW;     // 0..33
            const int rr = row / NPL;            // 0..4
            const int plane = row - rr * NPL;    // 0..18
            const float* base = (plane < IC)
                ? (xb + (size_t)plane * HH * WW)
                : (pb + (size_t)(plane - IC) * HH * WW);
            int gcol = j0 + ch * 4;
            if (gcol > WW - 4) gcol = WW - 4;    // clamp; garbage lands in unused cols
            const float* g = base + (size_t)(i0 + rr) * WW + gcol;
            __builtin_amdgcn_global_load_lds(
                (const __attribute__((address_space(1))) void*)g,
                (__attribute__((address_space(3))) void*)(lds + (size_t)cid * 4),
                16, 0, 0);
        }
    }

    // ---- A fragments (independent; overlaps staging latency) ----
    const int lane = tid & 63;
    const int wave = tid >> 6;       // 0..7
    const int p = lane & 15;
    const int c = lane >> 4;
    const int tc = wave * 16 + p;    // tile col 0..127

    short8 a0lo, a0hi, a1lo, a1hi;
    {
        const float4* k0v = (const float4*)(kern + (size_t)p * 64 + c * 8);
        const float4* k1v = (const float4*)(kern + (size_t)(16 + p) * 64 + c * 8);
        float4 v0a = k0v[0], v0b = k0v[1], v0c = k0v[8], v0d = k0v[9];
        float4 v1a = k1v[0], v1b = k1v[1], v1c = k1v[8], v1d = k1v[9];
        a0lo[0]=f2bf(v0a.x); a0lo[1]=f2bf(v0a.y); a0lo[2]=f2bf(v0a.z); a0lo[3]=f2bf(v0a.w);
        a0lo[4]=f2bf(v0b.x); a0lo[5]=f2bf(v0b.y); a0lo[6]=f2bf(v0b.z); a0lo[7]=f2bf(v0b.w);
        a0hi[0]=f2bf(v0c.x); a0hi[1]=f2bf(v0c.y); a0hi[2]=f2bf(v0c.z); a0hi[3]=f2bf(v0c.w);
        a0hi[4]=f2bf(v0d.x); a0hi[5]=f2bf(v0d.y); a0hi[6]=f2bf(v0d.z); a0hi[7]=f2bf(v0d.w);
        a1lo[0]=f2bf(v1a.x); a1lo[1]=f2bf(v1a.y); a1lo[2]=f2bf(v1a.z); a1lo[3]=f2bf(v1a.w);
        a1lo[4]=f2bf(v1b.x); a1lo[5]=f2bf(v1b.y); a1lo[6]=f2bf(v1b.z); a1lo[7]=f2bf(v1b.w);
        a1hi[0]=f2bf(v1c.x); a1hi[1]=f2bf(v1c.y); a1hi[2]=f2bf(v1c.z); a1hi[3]=f2bf(v1c.w);
        a1hi[4]=f2bf(v1d.x); a1hi[5]=f2bf(v1d.y); a1hi[6]=f2bf(v1d.z); a1hi[7]=f2bf(v1d.w);
    }

    __syncthreads();   // drain staging (single barrier per block)

    // ---- window partials from LDS ----
    float xs[4][RB], px0[4][RB], px1[4][RB], px2[4][RB];
    #pragma unroll
    for (int t = 0; t < 4; ++t)
        #pragma unroll
        for (int q = 0; q < RB; ++q) { xs[t][q]=0.f; px0[t][q]=0.f; px1[t][q]=0.f; px2[t][q]=0.f; }
    float c0v[RB], c1v[RB], c2v[RB];

    #pragma unroll
    for (int rr = 0; rr < TR; ++rr) {
        const float* lp0 = &lds[(rr * NPL + IC) * LCP + tc];
        const float* lp1 = &lds[(rr * NPL + IC + 1) * LCP + tc];
        const float* lp2 = &lds[(rr * NPL + IC + 2) * LCP + tc];
        const float pa0 = lp0[0], pm0 = lp0[1], pz0 = lp0[2];
        const float pa1 = lp1[0], pm1 = lp1[1], pz1 = lp1[2];
        const float pa2 = lp2[0], pm2 = lp2[1], pz2 = lp2[2];
        if (rr >= 1 && rr <= RB) { c0v[rr-1] = pm0; c1v[rr-1] = pm1; c2v[rr-1] = pm2; }
        #pragma unroll
        for (int t = 0; t < 4; ++t) {
            const int ic = (t >> 1) * 8 + 2 * c + (t & 1);
            const float* lx = &lds[(rr * NPL + ic) * LCP + tc];
            const float x0 = lx[0], x1 = lx[1], x2 = lx[2];
            const float rsx = x0 + x1 + x2;
            float r0 = pa0 * x0; r0 = fmaf(pm0, x1, r0); r0 = fmaf(pz0, x2, r0);
            float r1 = pa1 * x0; r1 = fmaf(pm1, x1, r1); r1 = fmaf(pz1, x2, r1);
            float r2 = pa2 * x0; r2 = fmaf(pm2, x1, r2); r2 = fmaf(pz2, x2, r2);
            #pragma unroll
            for (int q = 0; q < RB; ++q) {
                if (rr >= q && rr <= q + 2) {
                    xs[t][q] += rsx; px0[t][q] += r0; px1[t][q] += r1; px2[t][q] += r2;
                }
            }
        }
    }

    // ---- per output row: B fragments -> MFMA -> store ----
    const int j = j0 + tc;
    #pragma unroll
    for (int q = 0; q < RB; ++q) {
        short8 blo, bhi;
        #pragma unroll
        for (int t = 0; t < 4; ++t) {
            const short e0 = f2bf(fmaf(c0v[q], xs[t][q], -px0[t][q]));
            const short e1 = f2bf(fmaf(c1v[q], xs[t][q], -px1[t][q]));
            const short e2 = f2bf(fmaf(c2v[q], xs[t][q], -px2[t][q]));
            const short e3 = f2bf(xs[t][q]);
            const int sl = (t & 1) * 4;
            if (t < 2) { blo[sl+0]=e0; blo[sl+1]=e1; blo[sl+2]=e2; blo[sl+3]=e3; }
            else       { bhi[sl+0]=e0; bhi[sl+1]=e1; bhi[sl+2]=e2; bhi[sl+3]=e3; }
        }
        f32x4 acc0 = {0.f,0.f,0.f,0.f}, acc1 = {0.f,0.f,0.f,0.f};
        acc0 = __builtin_amdgcn_mfma_f32_16x16x32_bf16(a0lo, blo, acc0, 0, 0, 0);
        acc0 = __builtin_amdgcn_mfma_f32_16x16x32_bf16(a0hi, bhi, acc0, 0, 0, 0);
        acc1 = __builtin_amdgcn_mfma_f32_16x16x32_bf16(a1lo, blo, acc1, 0, 0, 0);
        acc1 = __builtin_amdgcn_mfma_f32_16x16x32_bf16(a1hi, bhi, acc1, 0, 0, 0);
        if (j < WP) {
            float* ob = out + (size_t)b * OC * HP * WP + (size_t)(i0 + q) * WP + j;
            #pragma unroll
            for (int r = 0; r < 4; ++r) {
                const int o = c * 4 + r;
                ob[(size_t)o * HP * WP]        = acc0[r];
                ob[(size_t)(o + 16) * HP * WP] = acc1[r];
            }
        }
    }
}

extern "C" void kernel_launch(void* const* d_in, const int* in_sizes, int n_in,
                              void* d_out, int out_size, void* d_ws, size_t ws_size,
                              hipStream_t stream)
{
    const float* x    = (const float*)d_in[0];
    const float* kern = (const float*)d_in[1];
    const float* pts  = (const float*)d_in[2];
    float* out = (float*)d_out;

    dim3 block(NTHR, 1, 1);
    // 4 col-groups x 21 row-tiles (last clamps to i0=59) x 16 batch
    dim3 grid(WW / TC, (HP + RB - 1) / RB, BS);   // 4 x 21 x 16 = 1344 blocks
    flex_conv_res<<<grid, block, 0, stream>>>(x, kern, pts, out);
}